// Round 1
// baseline (1717.291 us; speedup 1.0000x reference)
//
#include <hip/hip_runtime.h>
#include <cstddef>

#define NTOK   64      // tokens per window (8x8)
#define CDIM   192
#define ODIM   576     // 3*C
#define HEADS  6
#define DH     32
#define NTHR   384     // 6 waves, one wave per head in attention phase
#define KC     16      // k-chunk for GEMM staging
#define NCHUNK 12      // 192/16

// LDS layout (float offsets). Region A: xT -> qLDS -> attnOut. Region B: W-chunk -> kLDS -> projW-chunk. Region C: vLDS.
#define XS     68      // xT row stride (pad: breaks 64-float bank alias)
#define QS     65      // qLDS n-stride (bank = (d+n)%32, conflict-free reads)
#define AOS    196     // attnOut row stride (16B-aligned rows, bank rotate)
#define REG_B  13056   // 192*68
#define REG_C  25344   // REG_B + 6*64*32
#define LDS_FLOATS 37632  // 150,528 bytes total

__global__ __launch_bounds__(NTHR, 2)
void win_attn_fused(const float* __restrict__ x,
                    const float* __restrict__ mask,
                    const float* __restrict__ qkv_w,
                    const float* __restrict__ qkv_b,
                    const float* __restrict__ proj_w,
                    const float* __restrict__ proj_b,
                    const float* __restrict__ bias_table,
                    float* __restrict__ out)
{
    extern __shared__ float lds[];
    const int t = threadIdx.x;
    const int w = blockIdx.x;

    // ---------------- phase 0: load x[w] -> LDS transposed xT[c][n] ----------------
    {
        const float4* xg = reinterpret_cast<const float4*>(x + (size_t)w * (NTOK * CDIM));
        #pragma unroll
        for (int i = 0; i < 8; ++i) {
            int idx4 = t + i * NTHR;          // 3072 float4 total
            int n  = idx4 / 48;               // 48 float4 per token row
            int c4 = (idx4 % 48) * 4;
            float4 v = xg[idx4];
            lds[(c4 + 0) * XS + n] = v.x;
            lds[(c4 + 1) * XS + n] = v.y;
            lds[(c4 + 2) * XS + n] = v.z;
            lds[(c4 + 3) * XS + n] = v.w;
        }
    }
    __syncthreads();

    // ---------------- phase 1: qkv[n][o] = x[n][:] . qkv_w[o][:] + qkv_b[o] ----------------
    // thread tile: 12 outputs (o) x 8 rows (n)
    const int og = t % 48;
    const int ng = t / 48;
    const int o0 = og * 12;
    const int n0 = ng * 8;

    float acc[12][8];
    #pragma unroll
    for (int a = 0; a < 12; ++a)
        #pragma unroll
        for (int b = 0; b < 8; ++b) acc[a][b] = 0.0f;

    for (int kc = 0; kc < NCHUNK; ++kc) {
        // stage W chunk transposed: wT[ki][o] = qkv_w[o][kc*KC+ki]; 576*16 floats
        #pragma unroll
        for (int i = 0; i < 6; ++i) {
            int idx4 = t + i * NTHR;          // 2304 float4
            int o  = idx4 >> 2;
            int k4 = (idx4 & 3) * 4;
            float4 v = *reinterpret_cast<const float4*>(qkv_w + o * CDIM + kc * KC + k4);
            lds[REG_B + (k4 + 0) * ODIM + o] = v.x;
            lds[REG_B + (k4 + 1) * ODIM + o] = v.y;
            lds[REG_B + (k4 + 2) * ODIM + o] = v.z;
            lds[REG_B + (k4 + 3) * ODIM + o] = v.w;
        }
        __syncthreads();

        #pragma unroll
        for (int ki = 0; ki < KC; ++ki) {
            const float* xrow = &lds[(kc * KC + ki) * XS + n0];
            const float* wrow = &lds[REG_B + ki * ODIM + o0];
            float4 x0 = *reinterpret_cast<const float4*>(xrow);
            float4 x1 = *reinterpret_cast<const float4*>(xrow + 4);
            float4 w0 = *reinterpret_cast<const float4*>(wrow);
            float4 w1 = *reinterpret_cast<const float4*>(wrow + 4);
            float4 w2 = *reinterpret_cast<const float4*>(wrow + 8);
            float xv[8]  = {x0.x, x0.y, x0.z, x0.w, x1.x, x1.y, x1.z, x1.w};
            float wv[12] = {w0.x, w0.y, w0.z, w0.w, w1.x, w1.y, w1.z, w1.w,
                            w2.x, w2.y, w2.z, w2.w};
            #pragma unroll
            for (int a = 0; a < 12; ++a)
                #pragma unroll
                for (int b = 0; b < 8; ++b)
                    acc[a][b] = fmaf(wv[a], xv[b], acc[a][b]);
        }
        __syncthreads();
    }

    // epilogue: + bias, scatter q -> region A (overwrites dead xT), k -> B, v -> C
    {
        float bv[12];
        #pragma unroll
        for (int a = 0; a < 12; ++a) bv[a] = qkv_b[o0 + a];
        const int which = og / 16;            // thread tile never crosses q/k/v (192/12=16)
        const int rb = o0 - which * CDIM;     // 0..180 within q|k|v
        #pragma unroll
        for (int a = 0; a < 12; ++a) {
            int r = rb + a;                   // = h*32+d
            int h = r >> 5, d = r & 31;
            #pragma unroll
            for (int b = 0; b < 8; ++b) {
                float val = acc[a][b] + bv[a];
                int n = n0 + b;
                if (which == 0)      lds[r * QS + n] = val;
                else if (which == 1) lds[REG_B + (h * NTOK + n) * DH + d] = val;
                else                 lds[REG_C + (h * NTOK + n) * DH + d] = val;
            }
        }
    }
    __syncthreads();

    // ---------------- phase 2: logits + softmax. thread = (head, row) ----------------
    const int h2 = t >> 6;     // wave == head
    const int nn = t & 63;
    const int i1 = nn >> 3, j1 = nn & 7;

    float qr[32];
    #pragma unroll
    for (int d = 0; d < 32; ++d) qr[d] = lds[(h2 * DH + d) * QS + nn];
    __syncthreads();   // all q reads done before attnOut overwrites region A

    const float* maskRow = mask + ((size_t)w * NTOK + nn) * NTOK;
    const float scale = 0.17677669529663687f;   // 1/sqrt(32)
    float logit[64];
    #pragma unroll
    for (int m = 0; m < 64; ++m) {
        const float4* kr = reinterpret_cast<const float4*>(&lds[REG_B + (h2 * NTOK + m) * DH]);
        float4 s = make_float4(0.f, 0.f, 0.f, 0.f);
        #pragma unroll
        for (int c = 0; c < 8; ++c) {
            float4 kv = kr[c];
            s.x = fmaf(qr[4 * c + 0], kv.x, s.x);
            s.y = fmaf(qr[4 * c + 1], kv.y, s.y);
            s.z = fmaf(qr[4 * c + 2], kv.z, s.z);
            s.w = fmaf(qr[4 * c + 3], kv.w, s.w);
        }
        float dot = (s.x + s.y) + (s.z + s.w);
        int i2 = m >> 3, j2 = m & 7;
        int bidx = (i1 - i2 + 7) * 15 + (j1 - j2 + 7);
        logit[m] = fmaf(dot, scale, bias_table[bidx * HEADS + h2] + maskRow[m]);
    }

    float mx = logit[0];
    #pragma unroll
    for (int m = 1; m < 64; ++m) mx = fmaxf(mx, logit[m]);
    float sum = 0.f;
    #pragma unroll
    for (int m = 0; m < 64; ++m) { logit[m] = __expf(logit[m] - mx); sum += logit[m]; }
    const float inv = 1.0f / sum;
    #pragma unroll
    for (int m = 0; m < 64; ++m) logit[m] *= inv;

    // ---------------- phase 3: out_row = P . V ----------------
    float4 o4[8];
    #pragma unroll
    for (int c = 0; c < 8; ++c) o4[c] = make_float4(0.f, 0.f, 0.f, 0.f);
    #pragma unroll
    for (int m = 0; m < 64; ++m) {
        float p = logit[m];
        const float4* vr = reinterpret_cast<const float4*>(&lds[REG_C + (h2 * NTOK + m) * DH]);
        #pragma unroll
        for (int c = 0; c < 8; ++c) {
            float4 vv = vr[c];
            o4[c].x = fmaf(p, vv.x, o4[c].x);
            o4[c].y = fmaf(p, vv.y, o4[c].y);
            o4[c].z = fmaf(p, vv.z, o4[c].z);
            o4[c].w = fmaf(p, vv.w, o4[c].w);
        }
    }
    // write attn output row into region A: attnOut[n][h*32+d]
    #pragma unroll
    for (int c = 0; c < 8; ++c)
        *reinterpret_cast<float4*>(&lds[nn * AOS + h2 * DH + c * 4]) = o4[c];
    __syncthreads();

    // ---------------- phase 4: final = attnOut . proj_w^T + proj_b ----------------
    const int og2 = t % 24;        // 24 groups x 8 o
    const int ng2 = t / 24;        // 16 groups x 4 n
    const int oo0 = og2 * 8;
    const int nn0 = ng2 * 4;

    float4 pa[4][2];
    #pragma unroll
    for (int a = 0; a < 4; ++a) { pa[a][0] = make_float4(0.f,0.f,0.f,0.f); pa[a][1] = make_float4(0.f,0.f,0.f,0.f); }

    for (int kc = 0; kc < NCHUNK; ++kc) {
        // stage projW chunk transposed: wT2[ki][o] = proj_w[o][kc*KC+ki]; 192*16 floats
        #pragma unroll
        for (int i = 0; i < 2; ++i) {
            int idx4 = t + i * NTHR;          // 768 float4
            int o  = idx4 >> 2;
            int k4 = (idx4 & 3) * 4;
            float4 v = *reinterpret_cast<const float4*>(proj_w + o * CDIM + kc * KC + k4);
            lds[REG_B + (k4 + 0) * CDIM + o] = v.x;
            lds[REG_B + (k4 + 1) * CDIM + o] = v.y;
            lds[REG_B + (k4 + 2) * CDIM + o] = v.z;
            lds[REG_B + (k4 + 3) * CDIM + o] = v.w;
        }
        __syncthreads();

        #pragma unroll
        for (int ki = 0; ki < KC; ++ki) {
            int k = kc * KC + ki;
            const float* wrow = &lds[REG_B + ki * CDIM + oo0];
            float4 w0 = *reinterpret_cast<const float4*>(wrow);
            float4 w1 = *reinterpret_cast<const float4*>(wrow + 4);
            #pragma unroll
            for (int a = 0; a < 4; ++a) {
                float av = lds[(nn0 + a) * AOS + k];
                pa[a][0].x = fmaf(av, w0.x, pa[a][0].x);
                pa[a][0].y = fmaf(av, w0.y, pa[a][0].y);
                pa[a][0].z = fmaf(av, w0.z, pa[a][0].z);
                pa[a][0].w = fmaf(av, w0.w, pa[a][0].w);
                pa[a][1].x = fmaf(av, w1.x, pa[a][1].x);
                pa[a][1].y = fmaf(av, w1.y, pa[a][1].y);
                pa[a][1].z = fmaf(av, w1.z, pa[a][1].z);
                pa[a][1].w = fmaf(av, w1.w, pa[a][1].w);
            }
        }
        __syncthreads();
    }

    // epilogue: + proj bias, coalesced float4 stores
    {
        float4 pb0 = *reinterpret_cast<const float4*>(proj_b + oo0);
        float4 pb1 = *reinterpret_cast<const float4*>(proj_b + oo0 + 4);
        #pragma unroll
        for (int a = 0; a < 4; ++a) {
            size_t row = (size_t)w * NTOK + (nn0 + a);
            float4 r0 = pa[a][0]; r0.x += pb0.x; r0.y += pb0.y; r0.z += pb0.z; r0.w += pb0.w;
            float4 r1 = pa[a][1]; r1.x += pb1.x; r1.y += pb1.y; r1.z += pb1.z; r1.w += pb1.w;
            *reinterpret_cast<float4*>(out + row * CDIM + oo0)     = r0;
            *reinterpret_cast<float4*>(out + row * CDIM + oo0 + 4) = r1;
        }
    }
}

extern "C" void kernel_launch(void* const* d_in, const int* in_sizes, int n_in,
                              void* d_out, int out_size, void* d_ws, size_t ws_size,
                              hipStream_t stream) {
    const float* x          = (const float*)d_in[0];
    const float* mask       = (const float*)d_in[1];
    const float* qkv_w      = (const float*)d_in[2];
    const float* qkv_b      = (const float*)d_in[3];
    const float* proj_w     = (const float*)d_in[4];
    const float* proj_b     = (const float*)d_in[5];
    const float* bias_table = (const float*)d_in[6];
    float* out = (float*)d_out;

    const int nW = in_sizes[0] / (NTOK * CDIM);   // 4096
    const size_t shmem = LDS_FLOATS * sizeof(float);  // 150,528 B

    // opt-in to >64KB dynamic LDS (host-side attr set; not a stream op, graph-capture safe)
    hipFuncSetAttribute(reinterpret_cast<const void*>(win_attn_fused),
                        hipFuncAttributeMaxDynamicSharedMemorySize, (int)shmem);

    hipLaunchKernelGGL(win_attn_fused, dim3(nW), dim3(NTHR), shmem, stream,
                       x, mask, qkv_w, qkv_b, proj_w, proj_b, bias_table, out);
}

// Round 2
// 497.868 us; speedup vs baseline: 3.4493x; 3.4493x over previous
//
#include <hip/hip_runtime.h>
#include <cstddef>

// ---------------- problem constants ----------------
#define NTOK   64      // tokens per window
#define CDIM   192
#define ODIM   576     // 3*C
#define HEADS  6
#define DH     32
#define NTHR   384     // 6 waves; wave == head in attention phases
#define SCALE  0.17677669529663687f   // 1/sqrt(32)

// ws layout (bf16 weights)
#define WQ_ELEMS (ODIM*CDIM)   // 110592
#define WP_ELEMS (CDIM*CDIM)   // 36864

// LDS byte offsets (all bf16 tiles). AO overlays Xb (dead after QKV GEMM).
#define OFF_X  0          // [64][192] bf16, 384B rows -> 24576
#define OFF_Q  24576      // [64][192]
#define OFF_K  49152      // [64][192]
#define OFF_V  73728      // Vt [192][64], 128B rows
#define OFF_P  98304      // [6][64][64], 128B rows, 8192B per head
#define LDS_BYTES 147456  // 144 KiB

typedef __attribute__((ext_vector_type(8))) short bf16x8;
typedef __attribute__((ext_vector_type(4))) float f32x4;

__device__ __forceinline__ unsigned short f2b(float f) {
    union { float f; unsigned u; } v; v.f = f;
    unsigned r = v.u + 0x7FFFu + ((v.u >> 16) & 1u);   // round-to-nearest-even
    return (unsigned short)(r >> 16);
}

// XOR swizzle: spreads 16B slots of a column across banks. Rows are 384B or
// 128B (both multiples of 128B) so the XOR is bijective within each tile.
__device__ __forceinline__ char* swz384(char* base, int row, int byteInRow) {
    return base + ((row * 384 + byteInRow) ^ ((row & 7) << 4));
}
__device__ __forceinline__ char* swz128(char* base, int row, int byteInRow) {
    return base + ((row * 128 + byteInRow) ^ ((row & 7) << 4));
}

// ---------------- prep: fp32 weights -> bf16 in ws (scale folded into W_q) ----------------
__global__ __launch_bounds__(256)
void prep_weights(const float* __restrict__ qkv_w, const float* __restrict__ proj_w,
                  unsigned short* __restrict__ wq, unsigned short* __restrict__ wp)
{
    int i = blockIdx.x * 256 + threadIdx.x;       // grid covers WQ_ELEMS exactly
    if (i < WQ_ELEMS) {
        float v = qkv_w[i];
        if (i < CDIM * CDIM) v *= SCALE;          // q rows: o < 192  <=>  i < 192*192
        wq[i] = f2b(v);
    }
    if (i < WP_ELEMS) wp[i] = f2b(proj_w[i]);
}

// ---------------- fused window-attention, bf16 MFMA ----------------
__global__ __launch_bounds__(NTHR, 2)
void win_attn_mfma(const float* __restrict__ x,
                   const float* __restrict__ mask,
                   const unsigned short* __restrict__ wq,
                   const float* __restrict__ qkv_b,
                   const unsigned short* __restrict__ wp,
                   const float* __restrict__ proj_b,
                   const float* __restrict__ bias_table,
                   float* __restrict__ out)
{
    extern __shared__ char smem[];
    char* Xb = smem + OFF_X;   // also AO after attention
    char* Qb = smem + OFF_Q;
    char* Kb = smem + OFF_K;
    char* Vt = smem + OFF_V;

    const int t  = threadIdx.x;
    const int w  = blockIdx.x;
    const int wv = t >> 6;        // wave id == head id
    const int l  = t & 63;
    const int lo = l & 15;
    const int hi = l >> 4;

    // ---- phase 0: x[w] fp32 -> Xb bf16 [64][192] (swizzled) ----
    {
        const float* xw = x + (size_t)w * (NTOK * CDIM);
        #pragma unroll
        for (int it = 0; it < 4; ++it) {
            int c  = t + it * NTHR;           // 1536 chunks of 8 floats
            int n  = c / 24;                  // 24 chunks per row
            int cb = (c % 24) * 8;            // starting col
            float4 v0 = *(const float4*)(xw + c * 8);
            float4 v1 = *(const float4*)(xw + c * 8 + 4);
            bf16x8 p;
            p[0] = (short)f2b(v0.x); p[1] = (short)f2b(v0.y);
            p[2] = (short)f2b(v0.z); p[3] = (short)f2b(v0.w);
            p[4] = (short)f2b(v1.x); p[5] = (short)f2b(v1.y);
            p[6] = (short)f2b(v1.z); p[7] = (short)f2b(v1.w);
            *(bf16x8*)swz384(Xb, n, cb * 2) = p;
        }
    }
    __syncthreads();

    // ---- phase 1: QKV GEMM. D[n][o] = X . Wqkv^T (+bias). wave owns 6 o-tiles ----
    {
        f32x4 acc[4][6] = {};
        for (int ks = 0; ks < 6; ++ks) {
            bf16x8 af[4];
            #pragma unroll
            for (int nt = 0; nt < 4; ++nt)
                af[nt] = *(const bf16x8*)swz384(Xb, nt * 16 + lo, (ks * 32 + hi * 8) * 2);
            bf16x8 bfr[6];
            #pragma unroll
            for (int j = 0; j < 6; ++j) {
                int o = (wv * 6 + j) * 16 + lo;
                bfr[j] = *(const bf16x8*)(const void*)(wq + o * CDIM + ks * 32 + hi * 8);
            }
            #pragma unroll
            for (int nt = 0; nt < 4; ++nt)
                #pragma unroll
                for (int j = 0; j < 6; ++j)
                    acc[nt][j] = __builtin_amdgcn_mfma_f32_16x16x32_bf16(af[nt], bfr[j], acc[nt][j], 0, 0, 0);
        }
        // epilogue: +bias, scatter Q/K (row-major) and V (transposed) as bf16
        #pragma unroll
        for (int j = 0; j < 6; ++j) {
            int tile  = wv * 6 + j;
            int o     = tile * 16 + lo;
            int which = tile / 12;            // 0=q 1=k 2=v (tiles never straddle)
            int rem   = o - which * CDIM;     // h*32+d
            float be = qkv_b[o];
            if (which == 0) be *= SCALE;      // W_q was pre-scaled; bias too
            #pragma unroll
            for (int nt = 0; nt < 4; ++nt)
                #pragma unroll
                for (int r = 0; r < 4; ++r) {
                    int n = nt * 16 + hi * 4 + r;
                    unsigned short hv = f2b(acc[nt][j][r] + be);
                    if (which == 0)      *(unsigned short*)swz384(Qb, n, rem * 2) = hv;
                    else if (which == 1) *(unsigned short*)swz384(Kb, n, rem * 2) = hv;
                    else                 *(unsigned short*)swz128(Vt, rem, n * 2) = hv;
                }
        }
    }
    __syncthreads();

    // ---- phase 2: S = Q.K^T + bias + mask (C-init trick), wave = head ----
    const int h = wv;
    const float* maskW = mask + (size_t)w * (NTOK * NTOK);
    f32x4 cs[4][4];
    #pragma unroll
    for (int mt = 0; mt < 4; ++mt) {
        int m = mt * 16 + lo;
        int i2 = m >> 3, j2 = m & 7;
        #pragma unroll
        for (int nt = 0; nt < 4; ++nt)
            #pragma unroll
            for (int r = 0; r < 4; ++r) {
                int n = nt * 16 + hi * 4 + r;
                int i1 = n >> 3, j1 = n & 7;
                int bidx = ((i1 - i2 + 7) * 15 + (j1 - j2 + 7)) * HEADS + h;
                cs[nt][mt][r] = bias_table[bidx] + maskW[n * 64 + m];
            }
    }
    {
        bf16x8 qa[4], kb[4];
        #pragma unroll
        for (int nt = 0; nt < 4; ++nt)
            qa[nt] = *(const bf16x8*)swz384(Qb, nt * 16 + lo, (h * 32 + hi * 8) * 2);
        #pragma unroll
        for (int mt = 0; mt < 4; ++mt)
            kb[mt] = *(const bf16x8*)swz384(Kb, mt * 16 + lo, (h * 32 + hi * 8) * 2);
        #pragma unroll
        for (int nt = 0; nt < 4; ++nt)
            #pragma unroll
            for (int mt = 0; mt < 4; ++mt)
                cs[nt][mt] = __builtin_amdgcn_mfma_f32_16x16x32_bf16(qa[nt], kb[mt], cs[nt][mt], 0, 0, 0);
    }

    // ---- softmax over m; P -> LDS bf16; 1/sum deferred to PV epilogue ----
    float inv[4][4];
    char* Ph = smem + OFF_P + wv * 8192;
    #pragma unroll
    for (int nt = 0; nt < 4; ++nt)
        #pragma unroll
        for (int r = 0; r < 4; ++r) {
            float mx = fmaxf(fmaxf(cs[nt][0][r], cs[nt][1][r]),
                             fmaxf(cs[nt][2][r], cs[nt][3][r]));
            mx = fmaxf(mx, __shfl_xor(mx, 1));
            mx = fmaxf(mx, __shfl_xor(mx, 2));
            mx = fmaxf(mx, __shfl_xor(mx, 4));
            mx = fmaxf(mx, __shfl_xor(mx, 8));
            float s = 0.f;
            #pragma unroll
            for (int mt = 0; mt < 4; ++mt) {
                float e = __expf(cs[nt][mt][r] - mx);
                cs[nt][mt][r] = e;
                s += e;
            }
            s += __shfl_xor(s, 1);
            s += __shfl_xor(s, 2);
            s += __shfl_xor(s, 4);
            s += __shfl_xor(s, 8);
            inv[nt][r] = 1.0f / s;
            int n = nt * 16 + hi * 4 + r;
            #pragma unroll
            for (int mt = 0; mt < 4; ++mt)
                *(unsigned short*)swz128(Ph, n, (mt * 16 + lo) * 2) = f2b(cs[nt][mt][r]);
        }
    // wave-local RAW on P (no cross-wave sharing): drain LDS writes
    asm volatile("s_waitcnt lgkmcnt(0)" ::: "memory");

    // ---- phase 3: O = P.V ; AO (bf16) overlays Xb ----
    {
        f32x4 co[4][2] = {};
        #pragma unroll
        for (int ks = 0; ks < 2; ++ks) {
            bf16x8 pa[4], vb[2];
            #pragma unroll
            for (int nt = 0; nt < 4; ++nt)
                pa[nt] = *(const bf16x8*)swz128(Ph, nt * 16 + lo, (ks * 32 + hi * 8) * 2);
            #pragma unroll
            for (int dt = 0; dt < 2; ++dt)
                vb[dt] = *(const bf16x8*)swz128(Vt, h * 32 + dt * 16 + lo, (ks * 32 + hi * 8) * 2);
            #pragma unroll
            for (int nt = 0; nt < 4; ++nt)
                #pragma unroll
                for (int dt = 0; dt < 2; ++dt)
                    co[nt][dt] = __builtin_amdgcn_mfma_f32_16x16x32_bf16(pa[nt], vb[dt], co[nt][dt], 0, 0, 0);
        }
        #pragma unroll
        for (int nt = 0; nt < 4; ++nt)
            #pragma unroll
            for (int dt = 0; dt < 2; ++dt)
                #pragma unroll
                for (int r = 0; r < 4; ++r) {
                    int n = nt * 16 + hi * 4 + r;
                    int d = dt * 16 + lo;
                    *(unsigned short*)swz384(Xb, n, (h * 32 + d) * 2) =
                        f2b(co[nt][dt][r] * inv[nt][r]);
                }
    }
    __syncthreads();

    // ---- phase 4: out = AO . Wp^T + b. wave owns 2 o-tiles ----
    {
        f32x4 ac2[4][2] = {};
        for (int ks = 0; ks < 6; ++ks) {
            bf16x8 aa[4], bb[2];
            #pragma unroll
            for (int nt = 0; nt < 4; ++nt)
                aa[nt] = *(const bf16x8*)swz384(Xb, nt * 16 + lo, (ks * 32 + hi * 8) * 2);
            #pragma unroll
            for (int j = 0; j < 2; ++j) {
                int o2 = (wv * 2 + j) * 16 + lo;
                bb[j] = *(const bf16x8*)(const void*)(wp + o2 * CDIM + ks * 32 + hi * 8);
            }
            #pragma unroll
            for (int nt = 0; nt < 4; ++nt)
                #pragma unroll
                for (int j = 0; j < 2; ++j)
                    ac2[nt][j] = __builtin_amdgcn_mfma_f32_16x16x32_bf16(aa[nt], bb[j], ac2[nt][j], 0, 0, 0);
        }
        float* outW = out + (size_t)w * (NTOK * CDIM);
        #pragma unroll
        for (int j = 0; j < 2; ++j) {
            int o2 = (wv * 2 + j) * 16 + lo;
            float pb = proj_b[o2];
            #pragma unroll
            for (int nt = 0; nt < 4; ++nt)
                #pragma unroll
                for (int r = 0; r < 4; ++r) {
                    int n = nt * 16 + hi * 4 + r;
                    outW[n * CDIM + o2] = ac2[nt][j][r] + pb;
                }
        }
    }
}

extern "C" void kernel_launch(void* const* d_in, const int* in_sizes, int n_in,
                              void* d_out, int out_size, void* d_ws, size_t ws_size,
                              hipStream_t stream) {
    const float* x          = (const float*)d_in[0];
    const float* mask       = (const float*)d_in[1];
    const float* qkv_w      = (const float*)d_in[2];
    const float* qkv_b      = (const float*)d_in[3];
    const float* proj_w     = (const float*)d_in[4];
    const float* proj_b     = (const float*)d_in[5];
    const float* bias_table = (const float*)d_in[6];
    float* out = (float*)d_out;

    unsigned short* wq = (unsigned short*)d_ws;
    unsigned short* wp = wq + WQ_ELEMS;

    const int nW = in_sizes[0] / (NTOK * CDIM);   // 4096

    prep_weights<<<dim3((WQ_ELEMS + 255) / 256), dim3(256), 0, stream>>>(qkv_w, proj_w, wq, wp);

    hipFuncSetAttribute(reinterpret_cast<const void*>(win_attn_mfma),
                        hipFuncAttributeMaxDynamicSharedMemorySize, LDS_BYTES);
    hipLaunchKernelGGL(win_attn_mfma, dim3(nW), dim3(NTHR), LDS_BYTES, stream,
                       x, mask, wq, qkv_b, wp, proj_b, bias_table, out);
}